// Round 7
// baseline (393.535 us; speedup 1.0000x reference)
//
#include <hip/hip_runtime.h>

typedef unsigned short u16;
typedef __attribute__((ext_vector_type(4))) float f32x4;
typedef __attribute__((ext_vector_type(8))) short bf16x8;
typedef __attribute__((ext_vector_type(8))) u16 u16x8;
typedef __attribute__((ext_vector_type(4))) u16 u16x4v;

#define DI __device__ __forceinline__

DI u16 f2bf(float f) {
  unsigned int x = __float_as_uint(f);
  unsigned int r = (x + 0x7fffu + ((x >> 16) & 1u)) >> 16;
  return (u16)r;
}
DI float bf2f(u16 u) { return __uint_as_float(((unsigned int)u) << 16); }

// ---------------------------------------------------------------------------
// K0: pack weights. wqkvT[768][256] bf16 (row c = column c of [q|k*s|v]),
// bias[768] fp32 (k part pre-scaled), owT[256][256] bf16 (row c = col c of out_w)
// ---------------------------------------------------------------------------
__global__ __launch_bounds__(256) void pack_kernel(
    const float* __restrict__ qw, const float* __restrict__ qb,
    const float* __restrict__ kw, const float* __restrict__ kb,
    const float* __restrict__ vw, const float* __restrict__ vb,
    const float* __restrict__ ow,
    u16* __restrict__ wqkvT, float* __restrict__ bias, u16* __restrict__ owT)
{
  const int r = blockIdx.x;   // 0..1023
  const int t = threadIdx.x;  // 0..255
  if (r < 768) {
    const int p = r >> 8, c = r & 255;
    const float* wsrc = p == 0 ? qw : (p == 1 ? kw : vw);
    const float sc = (p == 1) ? 0.17677669529663687f : 1.0f;  // 1/sqrt(32)
    wqkvT[r * 256 + t] = f2bf(wsrc[t * 256 + c] * sc);
    if (t == 0) {
      const float* bs = p == 0 ? qb : (p == 1 ? kb : vb);
      bias[r] = bs[c] * sc;
    }
  } else {
    const int c = r - 768;
    owT[c * 256 + t] = f2bf(ow[t * 256 + c]);
  }
}

// ---------------------------------------------------------------------------
// K1: QKV projection + bias + RoPE, fused x fp32->bf16 staging.
// Grid 1024: one block per 64-row tile. Stage 64x256 A-tile (32 KB swizzled),
// loop 6 column groups; each wave owns 64 rows x 32 cols (acc[4][2]).
// Epilogue: IN-REGISTER RoPE — partner col^1 lives in lane^1 (__shfl_xor),
// sin/cos preloaded per mt (d = lr / 16+lr only), direct 2B stores
// (16 lanes x 2B = one full 32B sector per g-group; no RFO).
// ---------------------------------------------------------------------------
__global__ __launch_bounds__(256, 4) void qkv_gemm_kernel(
    const float* __restrict__ x, const u16* __restrict__ wT, const float* __restrict__ bias,
    const float* __restrict__ sinp, const float* __restrict__ cosp,
    u16* __restrict__ qr, u16* __restrict__ kr, u16* __restrict__ v)
{
  __shared__ u16 As[16384];        // 32 KB swizzled 64x256 bf16 tile
  const int t = threadIdx.x;
  const int wave = t >> 6, lane = t & 63;
  const int g = lane >> 4, lr = lane & 15;
  const int m0 = blockIdx.x * 64;

  {
    char* Abw = (char*)As;
#pragma unroll
    for (int i = 0; i < 16; ++i) {
      const int c = t + 256 * i;        // f32x4 chunk, 0..4095
      const int row = c >> 6, cf = c & 63;
      const float4 xv = *reinterpret_cast<const float4*>(x + (m0 + row) * 256 + cf * 4);
      u16x4v bv;
      bv.x = f2bf(xv.x); bv.y = f2bf(xv.y); bv.z = f2bf(xv.z); bv.w = f2bf(xv.w);
      *reinterpret_cast<u16x4v*>(Abw + row * 512 + ((cf * 8) ^ ((row & 7) << 4))) = bv;
    }
  }
  __syncthreads();

  const char* Ab = (const char*)As;

  for (int cg = 0; cg < 6; ++cg) {
    const int c0 = cg * 128;
    f32x4 acc[4][2];
#pragma unroll
    for (int i = 0; i < 4; ++i)
#pragma unroll
      for (int j = 0; j < 2; ++j) acc[i][j] = (f32x4){0.f, 0.f, 0.f, 0.f};

#pragma unroll
    for (int ks = 0; ks < 8; ++ks) {
      bf16x8 af[4], bfr[2];
#pragma unroll
      for (int mt = 0; mt < 4; ++mt) {
        const int rr = mt * 16 + lr;
        const int cb = (ks * 64 + g * 16) ^ ((rr & 7) << 4);
        af[mt] = *reinterpret_cast<const bf16x8*>(Ab + rr * 512 + cb);
      }
#pragma unroll
      for (int nt = 0; nt < 2; ++nt)
        bfr[nt] = *reinterpret_cast<const bf16x8*>(wT + (c0 + wave * 32 + nt * 16 + lr) * 256 + ks * 32 + g * 8);
#pragma unroll
      for (int mt = 0; mt < 4; ++mt)
#pragma unroll
        for (int nt = 0; nt < 2; ++nt)
          acc[mt][nt] = __builtin_amdgcn_mfma_f32_16x16x32_bf16(af[mt], bfr[nt], acc[mt][nt], 0, 0, 0);
    }

    const int colb = c0 + wave * 32;      // multiple of 32
    const int proj = colb >> 8;           // 0=q 1=k 2=v (uniform per wave)
    u16* dst = proj == 0 ? qr : (proj == 1 ? kr : v);
    const int e0 = colb & 255;
    const float bA = bias[colb + lr];
    const float bB = bias[colb + 16 + lr];
    const int odd = lr & 1;

#pragma unroll
    for (int mt = 0; mt < 4; ++mt) {
      const int row0 = m0 + mt * 16 + g * 4;   // rows row0..row0+3 (no 4096-wrap: m0 mult of 64)
      float snA[4], csA[4], snB[4], csB[4];
      if (proj < 2) {
        const int pos0 = row0 & 4095;
#pragma unroll
        for (int j = 0; j < 4; ++j) {
          snA[j] = sinp[(pos0 + j) * 32 + lr];
          csA[j] = cosp[(pos0 + j) * 32 + lr];
          snB[j] = sinp[(pos0 + j) * 32 + 16 + lr];
          csB[j] = cosp[(pos0 + j) * 32 + 16 + lr];
        }
      }
#pragma unroll
      for (int nt = 0; nt < 2; ++nt) {
#pragma unroll
        for (int j = 0; j < 4; ++j) {
          const float val = acc[mt][nt][j] + (nt ? bB : bA);
          float res;
          if (proj < 2) {
            const float prt = __shfl_xor(val, 1);
            const float sn = nt ? snB[j] : snA[j];
            const float cs = nt ? csB[j] : csA[j];
            res = odd ? (val * cs + prt * sn) : (val * cs - prt * sn);
          } else {
            res = val;
          }
          dst[(row0 + j) * 256 + e0 + nt * 16 + lr] = f2bf(res);
        }
      }
    }
  }
}

// ---------------------------------------------------------------------------
// K2/K3: axial attention. mode 0: over W (block = (b,h), token stride 256).
//        mode 1: over H (block = (b,w), token stride 16384).
// V staged TRANSPOSED in LDS (Vt[d][tok], tok XOR-swizzled by (d>>3)&7) so
// the PV B-fragment is one ds_read_b128. Pbuf is wave-private -> no barriers
// inside the head loop.
// ---------------------------------------------------------------------------
__global__ __launch_bounds__(256, 2) void attn_kernel(
    const u16* __restrict__ qr, const u16* __restrict__ kr, const u16* __restrict__ vsrc,
    const float* __restrict__ mask, u16* __restrict__ dst, const int mode)
{
  __shared__ u16 Pbuf[4][64][72];  // 36 KB per-wave P
  __shared__ u16 Vt[256][80];      // 40 KB transposed V (row = d, col = swizzled tok)
  const int t = threadIdx.x;
  const int wave = t >> 6, lane = t & 63;
  const int g = lane >> 4, lr = lane & 15;
  const int b = blockIdx.x >> 6, o = blockIdx.x & 63;
  const int base = (mode == 0) ? (b * 4096 + o * 64) * 256 : (b * 4096 + o) * 256;
  const int ts = (mode == 0) ? 256 : 16384;

#pragma unroll
  for (int i = 0; i < 8; ++i) {
    const int c = t + 256 * i;          // 16B chunk, 0..2047
    const int tok = c >> 5, ch = c & 31;
    const u16x8 val = *reinterpret_cast<const u16x8*>(vsrc + base + tok * ts + ch * 8);
    const int tc = tok ^ ((ch & 7) * 8);
#pragma unroll
    for (int j = 0; j < 8; ++j) Vt[ch * 8 + j][tc] = val[j];
  }
  __syncthreads();

  for (int hh = 0; hh < 2; ++hh) {
    const int n = wave * 2 + hh;
    bf16x8 qf[4], kf[4];
#pragma unroll
    for (int mt = 0; mt < 4; ++mt) {
      qf[mt] = *reinterpret_cast<const bf16x8*>(qr + base + (mt * 16 + lr) * ts + n * 32 + g * 8);
      kf[mt] = *reinterpret_cast<const bf16x8*>(kr + base + (mt * 16 + lr) * ts + n * 32 + g * 8);
    }
    const f32x4 zero = (f32x4){0.f, 0.f, 0.f, 0.f};
    f32x4 s[4][4];
#pragma unroll
    for (int mt = 0; mt < 4; ++mt)
#pragma unroll
      for (int nt = 0; nt < 4; ++nt)
        s[mt][nt] = __builtin_amdgcn_mfma_f32_16x16x32_bf16(qf[mt], kf[nt], zero, 0, 0, 0);

    const float* mp = mask + n * 4096;
#pragma unroll
    for (int mt = 0; mt < 4; ++mt) {
#pragma unroll
      for (int j = 0; j < 4; ++j) {
        const int r = mt * 16 + g * 4 + j;
#pragma unroll
        for (int nt = 0; nt < 4; ++nt)
          s[mt][nt][j] += mp[r * 64 + nt * 16 + lr];
        float m = fmaxf(fmaxf(s[mt][0][j], s[mt][1][j]), fmaxf(s[mt][2][j], s[mt][3][j]));
        m = fmaxf(m, __shfl_xor(m, 1));
        m = fmaxf(m, __shfl_xor(m, 2));
        m = fmaxf(m, __shfl_xor(m, 4));
        m = fmaxf(m, __shfl_xor(m, 8));
        float sum = 0.f;
#pragma unroll
        for (int nt = 0; nt < 4; ++nt) {
          const float p = __expf(s[mt][nt][j] - m);
          s[mt][nt][j] = p;
          sum += p;
        }
        sum += __shfl_xor(sum, 1);
        sum += __shfl_xor(sum, 2);
        sum += __shfl_xor(sum, 4);
        sum += __shfl_xor(sum, 8);
        const float rs = 1.f / sum;
#pragma unroll
        for (int nt = 0; nt < 4; ++nt)
          Pbuf[wave][r][nt * 16 + lr] = f2bf(s[mt][nt][j] * rs);
      }
    }

    f32x4 oacc[4][2];
#pragma unroll
    for (int mt = 0; mt < 4; ++mt)
#pragma unroll
      for (int nd = 0; nd < 2; ++nd) oacc[mt][nd] = zero;

#pragma unroll
    for (int kt = 0; kt < 2; ++kt) {
      bf16x8 pa[4];
#pragma unroll
      for (int mt = 0; mt < 4; ++mt)
        pa[mt] = *reinterpret_cast<const bf16x8*>(&Pbuf[wave][mt * 16 + lr][kt * 32 + g * 8]);
#pragma unroll
      for (int nd = 0; nd < 2; ++nd) {
        const int dcol = n * 32 + nd * 16 + lr;
        const bf16x8 vb = *reinterpret_cast<const bf16x8*>(
            &Vt[dcol][(kt * 32 + g * 8) ^ (((dcol >> 3) & 7) * 8)]);
#pragma unroll
        for (int mt = 0; mt < 4; ++mt)
          oacc[mt][nd] = __builtin_amdgcn_mfma_f32_16x16x32_bf16(pa[mt], vb, oacc[mt][nd], 0, 0, 0);
      }
    }
#pragma unroll
    for (int mt = 0; mt < 4; ++mt)
#pragma unroll
      for (int nd = 0; nd < 2; ++nd)
#pragma unroll
        for (int j = 0; j < 4; ++j)
          dst[base + (mt * 16 + g * 4 + j) * ts + n * 32 + nd * 16 + lr] = f2bf(oacc[mt][nd][j]);
  }
}

// ---------------------------------------------------------------------------
// K4: depthwise 5x5 conv (LePE). thread = 4 consecutive w-pixels x 8 channels.
// ---------------------------------------------------------------------------
__global__ __launch_bounds__(256) void lepe_kernel(
    const u16* __restrict__ v, const float* __restrict__ cw, const float* __restrict__ cb,
    u16* __restrict__ lepe)
{
  const int t = threadIdx.x;
  const int cg = t & 31, pg = t >> 5;     // 32 channel-groups x 8 pixel-groups
  const int c0 = cg * 8;
  const int rowi = blockIdx.x >> 1;       // b*64 + h, 0..1023
  const int w0 = (blockIdx.x & 1) * 32 + pg * 4;
  const int h = rowi & 63;

  float acc[4][8];
#pragma unroll
  for (int p = 0; p < 4; ++p)
#pragma unroll
    for (int j = 0; j < 8; ++j) acc[p][j] = 0.f;

#pragma unroll
  for (int dy = 0; dy < 5; ++dy) {
    const int hh = h + dy - 2;
    if ((unsigned)hh >= 64u) continue;
    const u16* vrow = v + (size_t)(rowi + dy - 2) * 64 * 256 + c0;
    float fin[8][8];
#pragma unroll
    for (int i = 0; i < 8; ++i) {
      const int ww = w0 - 2 + i;
      if ((unsigned)ww < 64u) {
        const u16x8 val = *reinterpret_cast<const u16x8*>(vrow + ww * 256);
#pragma unroll
        for (int j = 0; j < 8; ++j) fin[i][j] = bf2f(val[j]);
      } else {
#pragma unroll
        for (int j = 0; j < 8; ++j) fin[i][j] = 0.f;
      }
    }
#pragma unroll
    for (int dx = 0; dx < 5; ++dx) {
      const float* wp = cw + (dy * 5 + dx) * 256 + c0;
      const float4 wA = *reinterpret_cast<const float4*>(wp);
      const float4 wB = *reinterpret_cast<const float4*>(wp + 4);
      const float wv[8] = {wA.x, wA.y, wA.z, wA.w, wB.x, wB.y, wB.z, wB.w};
#pragma unroll
      for (int p = 0; p < 4; ++p)
#pragma unroll
        for (int j = 0; j < 8; ++j)
          acc[p][j] += fin[p + dx][j] * wv[j];
    }
  }

#pragma unroll
  for (int p = 0; p < 4; ++p) {
    u16x8 r;
#pragma unroll
    for (int j = 0; j < 8; ++j) r[j] = f2bf(acc[p][j] + cb[c0 + j]);
    *reinterpret_cast<u16x8*>(lepe + ((size_t)rowi * 64 + w0 + p) * 256 + c0) = r;
  }
}

// ---------------------------------------------------------------------------
// K5: out = (attn_out + lepe) @ out_w + out_b. Grid 1024: 64-row tiles,
// fused add reg-staged into swizzled 32 KB LDS; wave owns 32 cols per cg.
// ---------------------------------------------------------------------------
__global__ __launch_bounds__(256, 6) void out_gemm_kernel(
    const u16* __restrict__ ao, const u16* __restrict__ lep, const u16* __restrict__ owT,
    const float* __restrict__ ob, float* __restrict__ out)
{
  __shared__ u16 As[16384];  // 32 KB
  const int t = threadIdx.x;
  const int wave = t >> 6, lane = t & 63;
  const int g = lane >> 4, lr = lane & 15;
  const int m0 = blockIdx.x * 64;

  char* Abw = (char*)As;
#pragma unroll
  for (int i = 0; i < 8; ++i) {
    const int c = t + 256 * i;          // 16B chunk, 0..2047
    const int row = c >> 5, bc = (c & 31) << 4;
    const int off = (m0 + row) * 256 + (c & 31) * 8;
    const u16x8 a = *reinterpret_cast<const u16x8*>(ao + off);
    const u16x8 l = *reinterpret_cast<const u16x8*>(lep + off);
    u16x8 s;
#pragma unroll
    for (int j = 0; j < 8; ++j) s[j] = f2bf(bf2f(a[j]) + bf2f(l[j]));
    *reinterpret_cast<u16x8*>(Abw + row * 512 + (bc ^ ((row & 7) << 4))) = s;
  }
  __syncthreads();

  const char* Ab = (const char*)As;
  for (int cg = 0; cg < 2; ++cg) {
    const int c0 = cg * 128 + wave * 32;
    f32x4 acc[4][2];
#pragma unroll
    for (int i = 0; i < 4; ++i)
#pragma unroll
      for (int j = 0; j < 2; ++j) acc[i][j] = (f32x4){0.f, 0.f, 0.f, 0.f};

#pragma unroll
    for (int ks = 0; ks < 8; ++ks) {
      bf16x8 af[4], bfr[2];
#pragma unroll
      for (int mt = 0; mt < 4; ++mt) {
        const int rr = mt * 16 + lr;
        const int cb = (ks * 64 + g * 16) ^ ((rr & 7) << 4);
        af[mt] = *reinterpret_cast<const bf16x8*>(Ab + rr * 512 + cb);
      }
#pragma unroll
      for (int nt = 0; nt < 2; ++nt)
        bfr[nt] = *reinterpret_cast<const bf16x8*>(owT + (c0 + nt * 16 + lr) * 256 + ks * 32 + g * 8);
#pragma unroll
      for (int mt = 0; mt < 4; ++mt)
#pragma unroll
        for (int nt = 0; nt < 2; ++nt)
          acc[mt][nt] = __builtin_amdgcn_mfma_f32_16x16x32_bf16(af[mt], bfr[nt], acc[mt][nt], 0, 0, 0);
    }

#pragma unroll
    for (int mt = 0; mt < 4; ++mt) {
#pragma unroll
      for (int nt = 0; nt < 2; ++nt) {
        const int col = c0 + nt * 16 + lr;
        const float bc2 = ob[col];
#pragma unroll
        for (int j = 0; j < 4; ++j) {
          const int tok = m0 + mt * 16 + g * 4 + j;
          out[tok * 256 + col] = acc[mt][nt][j] + bc2;
        }
      }
    }
  }
}

// ---------------------------------------------------------------------------
extern "C" void kernel_launch(void* const* d_in, const int* in_sizes, int n_in,
                              void* d_out, int out_size, void* d_ws, size_t ws_size,
                              hipStream_t stream)
{
  const float* x      = (const float*)d_in[0];
  const float* sinp   = (const float*)d_in[1];
  const float* cosp   = (const float*)d_in[2];
  const float* mask_h = (const float*)d_in[3];
  const float* mask_w = (const float*)d_in[4];
  const float* q_w    = (const float*)d_in[5];
  const float* q_b    = (const float*)d_in[6];
  const float* k_w    = (const float*)d_in[7];
  const float* k_b    = (const float*)d_in[8];
  const float* v_w    = (const float*)d_in[9];
  const float* v_b    = (const float*)d_in[10];
  const float* lepe_w = (const float*)d_in[11];
  const float* lepe_b = (const float*)d_in[12];
  const float* out_w  = (const float*)d_in[13];
  const float* out_b  = (const float*)d_in[14];

  unsigned char* ws = (unsigned char*)d_ws;
  const size_t SZ = 33554432;  // 65536*256*2 bytes
  u16* qr    = (u16*)(ws);
  u16* kr    = (u16*)(ws + SZ);
  u16* vv    = (u16*)(ws + 2 * SZ);
  u16* v1    = (u16*)(ws + 3 * SZ);
  u16* lepe  = (u16*)(ws + 4 * SZ);
  u16* wqkvT = (u16*)(ws + 5 * SZ);
  u16* owT   = (u16*)(ws + 5 * SZ + 393216);
  float* bias = (float*)(ws + 5 * SZ + 393216 + 131072);
  u16* attn_out = vv;  // v is dead after conv + attnW

  pack_kernel<<<1024, 256, 0, stream>>>(q_w, q_b, k_w, k_b, v_w, v_b, out_w, wqkvT, bias, owT);
  qkv_gemm_kernel<<<1024, 256, 0, stream>>>(x, wqkvT, bias, sinp, cosp, qr, kr, vv);
  lepe_kernel<<<2048, 256, 0, stream>>>(vv, lepe_w, lepe_b, lepe);
  attn_kernel<<<1024, 256, 0, stream>>>(qr, kr, vv, mask_w, v1, 0);
  attn_kernel<<<1024, 256, 0, stream>>>(qr, kr, v1, mask_h, attn_out, 1);
  out_gemm_kernel<<<1024, 256, 0, stream>>>(attn_out, lepe, owT, out_b, (float*)d_out);
}

// Round 8
// 269.118 us; speedup vs baseline: 1.4623x; 1.4623x over previous
//
#include <hip/hip_runtime.h>

typedef unsigned short u16;
typedef __attribute__((ext_vector_type(4))) float f32x4;
typedef __attribute__((ext_vector_type(8))) short bf16x8;
typedef __attribute__((ext_vector_type(8))) u16 u16x8;
typedef __attribute__((ext_vector_type(4))) u16 u16x4v;

#define DI __device__ __forceinline__

DI u16 f2bf(float f) {
  unsigned int x = __float_as_uint(f);
  unsigned int r = (x + 0x7fffu + ((x >> 16) & 1u)) >> 16;
  return (u16)r;
}
DI float bf2f(u16 u) { return __uint_as_float(((unsigned int)u) << 16); }

// ---------------------------------------------------------------------------
// K0: pack weights. wqkvT[768][256] bf16 (row c = column c of [q|k*s|v]),
// bias[768] fp32 (k part pre-scaled), owT[256][256] bf16 (row c = col c of out_w)
// ---------------------------------------------------------------------------
__global__ __launch_bounds__(256) void pack_kernel(
    const float* __restrict__ qw, const float* __restrict__ qb,
    const float* __restrict__ kw, const float* __restrict__ kb,
    const float* __restrict__ vw, const float* __restrict__ vb,
    const float* __restrict__ ow,
    u16* __restrict__ wqkvT, float* __restrict__ bias, u16* __restrict__ owT)
{
  const int r = blockIdx.x;   // 0..1023
  const int t = threadIdx.x;  // 0..255
  if (r < 768) {
    const int p = r >> 8, c = r & 255;
    const float* wsrc = p == 0 ? qw : (p == 1 ? kw : vw);
    const float sc = (p == 1) ? 0.17677669529663687f : 1.0f;  // 1/sqrt(32)
    wqkvT[r * 256 + t] = f2bf(wsrc[t * 256 + c] * sc);
    if (t == 0) {
      const float* bs = p == 0 ? qb : (p == 1 ? kb : vb);
      bias[r] = bs[c] * sc;
    }
  } else {
    const int c = r - 768;
    owT[c * 256 + t] = f2bf(ow[t * 256 + c]);
  }
}

// ---------------------------------------------------------------------------
// K1: QKV projection + bias + RoPE, fused fp32->bf16 staging.
// Grid 512: one block per 128-row tile (R3 structure, best measured).
// Stage 128x256 A-tile once (64 KB, reg-staged swizzled ds_write), loop 6
// column groups; wave owns 64x64 (acc[4][4]).
// Epilogue: per-wave 16x64 f32 transpose slab, XOR swizzle
//   phys_col = c ^ 8*(row&3) ^ 16*((row>>2)&1)
// -> writes 2 lanes/bank (free), reads uniform 16/bank (LDS BW floor).
// Lane then owns 8 consecutive columns of one token: RoPE in-lane, sin/cos
// 16B vector loads, stores u16x8 (16B, no RFO).
// ---------------------------------------------------------------------------
__global__ __launch_bounds__(256, 2) void qkv_gemm_kernel(
    const float* __restrict__ x, const u16* __restrict__ wT, const float* __restrict__ bias,
    const float* __restrict__ sinp, const float* __restrict__ cosp,
    u16* __restrict__ qr, u16* __restrict__ kr, u16* __restrict__ v)
{
  __shared__ u16 As[32768];      // 64 KB swizzled 128x256 bf16 tile
  __shared__ float Tr[4][1024];  // 16 KB: per-wave 16x64 f32 transpose slab
  const int t = threadIdx.x;
  const int wave = t >> 6, lane = t & 63;
  const int g = lane >> 4, lr = lane & 15;
  const int wr = wave >> 1, wc = wave & 1;
  const int m0 = blockIdx.x * 128;

  {  // fused convert + stage: 32 float4 chunks per thread
    char* Abw = (char*)As;
#pragma unroll
    for (int i = 0; i < 32; ++i) {
      const int c = t + 256 * i;        // f32x4 chunk, 0..8191
      const int row = c >> 6, cf = c & 63;
      const float4 xv = *reinterpret_cast<const float4*>(x + (m0 + row) * 256 + cf * 4);
      u16x4v bv;
      bv.x = f2bf(xv.x); bv.y = f2bf(xv.y); bv.z = f2bf(xv.z); bv.w = f2bf(xv.w);
      *reinterpret_cast<u16x4v*>(Abw + row * 512 + ((cf * 8) ^ ((row & 7) << 4))) = bv;
    }
  }
  __syncthreads();

  const char* Ab = (const char*)As;
  float* Trw = Tr[wave];
  const int tau = lane >> 3;        // 0..7: token sub-row for epilogue reads
  const int kap = lane & 7;         // 0..7: 8-col chunk for epilogue reads

  for (int cg = 0; cg < 6; ++cg) {
    const int c0 = cg * 128;
    f32x4 acc[4][4];
#pragma unroll
    for (int i = 0; i < 4; ++i)
#pragma unroll
      for (int j = 0; j < 4; ++j) acc[i][j] = (f32x4){0.f, 0.f, 0.f, 0.f};

#pragma unroll
    for (int ks = 0; ks < 8; ++ks) {
      bf16x8 af[4], bfr[4];
#pragma unroll
      for (int mt = 0; mt < 4; ++mt) {
        const int rr = wr * 64 + mt * 16 + lr;
        const int cb = (ks * 64 + g * 16) ^ ((rr & 7) << 4);
        af[mt] = *reinterpret_cast<const bf16x8*>(Ab + rr * 512 + cb);
      }
#pragma unroll
      for (int nt = 0; nt < 4; ++nt)
        bfr[nt] = *reinterpret_cast<const bf16x8*>(wT + (c0 + wc * 64 + nt * 16 + lr) * 256 + ks * 32 + g * 8);
#pragma unroll
      for (int mt = 0; mt < 4; ++mt)
#pragma unroll
        for (int nt = 0; nt < 4; ++nt)
          acc[mt][nt] = __builtin_amdgcn_mfma_f32_16x16x32_bf16(af[mt], bfr[nt], acc[mt][nt], 0, 0, 0);
    }

    const int colb = c0 + wc * 64;
    const int proj = colb >> 8;  // 0=q 1=k 2=v (uniform per wave)
    u16* dst = proj == 0 ? qr : (proj == 1 ? kr : v);
    const int e0 = (colb & 255) + kap * 8;

    float bcv[4];
#pragma unroll
    for (int nt = 0; nt < 4; ++nt) bcv[nt] = bias[colb + nt * 16 + lr];

#pragma unroll
    for (int mt = 0; mt < 4; ++mt) {
      // write slab: row = g*4+j, c = nt*16+lr, phys = c ^ 8j ^ 16(g&1)
      const int sigw = (8 * ((g * 4) & 3)) ^ (16 * (g & 1));  // = 16*(g&1); j added below
#pragma unroll
      for (int nt = 0; nt < 4; ++nt)
#pragma unroll
        for (int j = 0; j < 4; ++j)
          Trw[(g * 4 + j) * 64 + ((nt * 16 + lr) ^ (8 * j) ^ (16 * (g & 1)))] =
              acc[mt][nt][j] + bcv[nt];
      (void)sigw;
      asm volatile("s_waitcnt lgkmcnt(0)" ::: "memory");
#pragma unroll
      for (int r2 = 0; r2 < 2; ++r2) {
        const int row = tau + 8 * r2;                    // 0..15
        const int sig = (8 * (row & 3)) ^ (16 * ((row >> 2) & 1));
        const int rb = row * 64 + ((kap * 8) ^ sig);
        const float4 v0 = *reinterpret_cast<const float4*>(Trw + rb);
        const float4 v1 = *reinterpret_cast<const float4*>(Trw + rb + 4);
        const int tok = m0 + wr * 64 + mt * 16 + row;
        u16x8 o;
        if (proj < 2) {
          const int pos = tok & 4095;        // h*64 + w
          const int d0 = (kap * 8) & 31;     // head-dim base (multiple of 8)
          const float* sp2 = sinp + pos * 32 + d0;
          const float* cp2 = cosp + pos * 32 + d0;
          {
            const float4 s0 = *reinterpret_cast<const float4*>(sp2);
            const float4 cA = *reinterpret_cast<const float4*>(cp2);
            o[0] = f2bf(v0.x * cA.x - v0.y * s0.x);
            o[1] = f2bf(v0.y * cA.y + v0.x * s0.y);
            o[2] = f2bf(v0.z * cA.z - v0.w * s0.z);
            o[3] = f2bf(v0.w * cA.w + v0.z * s0.w);
          }
          {
            const float4 s1 = *reinterpret_cast<const float4*>(sp2 + 4);
            const float4 cB = *reinterpret_cast<const float4*>(cp2 + 4);
            o[4] = f2bf(v1.x * cB.x - v1.y * s1.x);
            o[5] = f2bf(v1.y * cB.y + v1.x * s1.y);
            o[6] = f2bf(v1.z * cB.z - v1.w * s1.z);
            o[7] = f2bf(v1.w * cB.w + v1.z * s1.w);
          }
        } else {
          o[0] = f2bf(v0.x); o[1] = f2bf(v0.y); o[2] = f2bf(v0.z); o[3] = f2bf(v0.w);
          o[4] = f2bf(v1.x); o[5] = f2bf(v1.y); o[6] = f2bf(v1.z); o[7] = f2bf(v1.w);
        }
        *reinterpret_cast<u16x8*>(dst + tok * 256 + e0) = o;
      }
      asm volatile("s_waitcnt lgkmcnt(0)" ::: "memory");  // drain before next mt overwrites Tr
    }
  }
}

// ---------------------------------------------------------------------------
// K2/K3: axial attention. mode 0: over W (block = (b,h), token stride 256).
//        mode 1: over H (block = (b,w), token stride 16384).
// V staged TRANSPOSED in LDS (Vt[d][tok], tok XOR-swizzled by (d>>3)&7) so
// the PV B-fragment is one ds_read_b128. Pbuf is wave-private -> no barriers
// inside the head loop.
// ---------------------------------------------------------------------------
__global__ __launch_bounds__(256, 2) void attn_kernel(
    const u16* __restrict__ qr, const u16* __restrict__ kr, const u16* __restrict__ vsrc,
    const float* __restrict__ mask, u16* __restrict__ dst, const int mode)
{
  __shared__ u16 Pbuf[4][64][72];  // 36 KB per-wave P
  __shared__ u16 Vt[256][80];      // 40 KB transposed V (row = d, col = swizzled tok)
  const int t = threadIdx.x;
  const int wave = t >> 6, lane = t & 63;
  const int g = lane >> 4, lr = lane & 15;
  const int b = blockIdx.x >> 6, o = blockIdx.x & 63;
  const int base = (mode == 0) ? (b * 4096 + o * 64) * 256 : (b * 4096 + o) * 256;
  const int ts = (mode == 0) ? 256 : 16384;

#pragma unroll
  for (int i = 0; i < 8; ++i) {
    const int c = t + 256 * i;          // 16B chunk, 0..2047
    const int tok = c >> 5, ch = c & 31;
    const u16x8 val = *reinterpret_cast<const u16x8*>(vsrc + base + tok * ts + ch * 8);
    const int tc = tok ^ ((ch & 7) * 8);
#pragma unroll
    for (int j = 0; j < 8; ++j) Vt[ch * 8 + j][tc] = val[j];
  }
  __syncthreads();

  for (int hh = 0; hh < 2; ++hh) {
    const int n = wave * 2 + hh;
    bf16x8 qf[4], kf[4];
#pragma unroll
    for (int mt = 0; mt < 4; ++mt) {
      qf[mt] = *reinterpret_cast<const bf16x8*>(qr + base + (mt * 16 + lr) * ts + n * 32 + g * 8);
      kf[mt] = *reinterpret_cast<const bf16x8*>(kr + base + (mt * 16 + lr) * ts + n * 32 + g * 8);
    }
    const f32x4 zero = (f32x4){0.f, 0.f, 0.f, 0.f};
    f32x4 s[4][4];
#pragma unroll
    for (int mt = 0; mt < 4; ++mt)
#pragma unroll
      for (int nt = 0; nt < 4; ++nt)
        s[mt][nt] = __builtin_amdgcn_mfma_f32_16x16x32_bf16(qf[mt], kf[nt], zero, 0, 0, 0);

    const float* mp = mask + n * 4096;
#pragma unroll
    for (int mt = 0; mt < 4; ++mt) {
#pragma unroll
      for (int j = 0; j < 4; ++j) {
        const int r = mt * 16 + g * 4 + j;
#pragma unroll
        for (int nt = 0; nt < 4; ++nt)
          s[mt][nt][j] += mp[r * 64 + nt * 16 + lr];
        float m = fmaxf(fmaxf(s[mt][0][j], s[mt][1][j]), fmaxf(s[mt][2][j], s[mt][3][j]));
        m = fmaxf(m, __shfl_xor(m, 1));
        m = fmaxf(m, __shfl_xor(m, 2));
        m = fmaxf(m, __shfl_xor(m, 4));
        m = fmaxf(m, __shfl_xor(m, 8));
        float sum = 0.f;
#pragma unroll
        for (int nt = 0; nt < 4; ++nt) {
          const float p = __expf(s[mt][nt][j] - m);
          s[mt][nt][j] = p;
          sum += p;
        }
        sum += __shfl_xor(sum, 1);
        sum += __shfl_xor(sum, 2);
        sum += __shfl_xor(sum, 4);
        sum += __shfl_xor(sum, 8);
        const float rs = 1.f / sum;
#pragma unroll
        for (int nt = 0; nt < 4; ++nt)
          Pbuf[wave][r][nt * 16 + lr] = f2bf(s[mt][nt][j] * rs);
      }
    }

    f32x4 oacc[4][2];
#pragma unroll
    for (int mt = 0; mt < 4; ++mt)
#pragma unroll
      for (int nd = 0; nd < 2; ++nd) oacc[mt][nd] = zero;

#pragma unroll
    for (int kt = 0; kt < 2; ++kt) {
      bf16x8 pa[4];
#pragma unroll
      for (int mt = 0; mt < 4; ++mt)
        pa[mt] = *reinterpret_cast<const bf16x8*>(&Pbuf[wave][mt * 16 + lr][kt * 32 + g * 8]);
#pragma unroll
      for (int nd = 0; nd < 2; ++nd) {
        const int dcol = n * 32 + nd * 16 + lr;
        const bf16x8 vb = *reinterpret_cast<const bf16x8*>(
            &Vt[dcol][(kt * 32 + g * 8) ^ (((dcol >> 3) & 7) * 8)]);
#pragma unroll
        for (int mt = 0; mt < 4; ++mt)
          oacc[mt][nd] = __builtin_amdgcn_mfma_f32_16x16x32_bf16(pa[mt], vb, oacc[mt][nd], 0, 0, 0);
      }
    }
#pragma unroll
    for (int mt = 0; mt < 4; ++mt)
#pragma unroll
      for (int nd = 0; nd < 2; ++nd)
#pragma unroll
        for (int j = 0; j < 4; ++j)
          dst[base + (mt * 16 + g * 4 + j) * ts + n * 32 + nd * 16 + lr] = f2bf(oacc[mt][nd][j]);
  }
}

// ---------------------------------------------------------------------------
// K4: depthwise 5x5 conv (LePE). thread = 4 consecutive w-pixels x 8 channels.
// ---------------------------------------------------------------------------
__global__ __launch_bounds__(256) void lepe_kernel(
    const u16* __restrict__ v, const float* __restrict__ cw, const float* __restrict__ cb,
    u16* __restrict__ lepe)
{
  const int t = threadIdx.x;
  const int cg = t & 31, pg = t >> 5;     // 32 channel-groups x 8 pixel-groups
  const int c0 = cg * 8;
  const int rowi = blockIdx.x >> 1;       // b*64 + h, 0..1023
  const int w0 = (blockIdx.x & 1) * 32 + pg * 4;
  const int h = rowi & 63;

  float acc[4][8];
#pragma unroll
  for (int p = 0; p < 4; ++p)
#pragma unroll
    for (int j = 0; j < 8; ++j) acc[p][j] = 0.f;

#pragma unroll
  for (int dy = 0; dy < 5; ++dy) {
    const int hh = h + dy - 2;
    if ((unsigned)hh >= 64u) continue;
    const u16* vrow = v + (size_t)(rowi + dy - 2) * 64 * 256 + c0;
    float fin[8][8];
#pragma unroll
    for (int i = 0; i < 8; ++i) {
      const int ww = w0 - 2 + i;
      if ((unsigned)ww < 64u) {
        const u16x8 val = *reinterpret_cast<const u16x8*>(vrow + ww * 256);
#pragma unroll
        for (int j = 0; j < 8; ++j) fin[i][j] = bf2f(val[j]);
      } else {
#pragma unroll
        for (int j = 0; j < 8; ++j) fin[i][j] = 0.f;
      }
    }
#pragma unroll
    for (int dx = 0; dx < 5; ++dx) {
      const float* wp = cw + (dy * 5 + dx) * 256 + c0;
      const float4 wA = *reinterpret_cast<const float4*>(wp);
      const float4 wB = *reinterpret_cast<const float4*>(wp + 4);
      const float wv[8] = {wA.x, wA.y, wA.z, wA.w, wB.x, wB.y, wB.z, wB.w};
#pragma unroll
      for (int p = 0; p < 4; ++p)
#pragma unroll
        for (int j = 0; j < 8; ++j)
          acc[p][j] += fin[p + dx][j] * wv[j];
    }
  }

#pragma unroll
  for (int p = 0; p < 4; ++p) {
    u16x8 r;
#pragma unroll
    for (int j = 0; j < 8; ++j) r[j] = f2bf(acc[p][j] + cb[c0 + j]);
    *reinterpret_cast<u16x8*>(lepe + ((size_t)rowi * 64 + w0 + p) * 256 + c0) = r;
  }
}

// ---------------------------------------------------------------------------
// K5: out = (attn_out + lepe) @ out_w + out_b. Grid 1024: 64-row tiles,
// fused add reg-staged into swizzled 32 KB LDS; wave owns 32 cols per cg.
// ---------------------------------------------------------------------------
__global__ __launch_bounds__(256, 6) void out_gemm_kernel(
    const u16* __restrict__ ao, const u16* __restrict__ lep, const u16* __restrict__ owT,
    const float* __restrict__ ob, float* __restrict__ out)
{
  __shared__ u16 As[16384];  // 32 KB
  const int t = threadIdx.x;
  const int wave = t >> 6, lane = t & 63;
  const int g = lane >> 4, lr = lane & 15;
  const int m0 = blockIdx.x * 64;

  char* Abw = (char*)As;
#pragma unroll
  for (int i = 0; i < 8; ++i) {
    const int c = t + 256 * i;          // 16B chunk, 0..2047
    const int row = c >> 5, bc = (c & 31) << 4;
    const int off = (m0 + row) * 256 + (c & 31) * 8;
    const u16x8 a = *reinterpret_cast<const u16x8*>(ao + off);
    const u16x8 l = *reinterpret_cast<const u16x8*>(lep + off);
    u16x8 s;
#pragma unroll
    for (int j = 0; j < 8; ++j) s[j] = f2bf(bf2f(a[j]) + bf2f(l[j]));
    *reinterpret_cast<u16x8*>(Abw + row * 512 + (bc ^ ((row & 7) << 4))) = s;
  }
  __syncthreads();

  const char* Ab = (const char*)As;
  for (int cg = 0; cg < 2; ++cg) {
    const int c0 = cg * 128 + wave * 32;
    f32x4 acc[4][2];
#pragma unroll
    for (int i = 0; i < 4; ++i)
#pragma unroll
      for (int j = 0; j < 2; ++j) acc[i][j] = (f32x4){0.f, 0.f, 0.f, 0.f};

#pragma unroll
    for (int ks = 0; ks < 8; ++ks) {
      bf16x8 af[4], bfr[2];
#pragma unroll
      for (int mt = 0; mt < 4; ++mt) {
        const int rr = mt * 16 + lr;
        const int cb = (ks * 64 + g * 16) ^ ((rr & 7) << 4);
        af[mt] = *reinterpret_cast<const bf16x8*>(Ab + rr * 512 + cb);
      }
#pragma unroll
      for (int nt = 0; nt < 2; ++nt)
        bfr[nt] = *reinterpret_cast<const bf16x8*>(owT + (c0 + nt * 16 + lr) * 256 + ks * 32 + g * 8);
#pragma unroll
      for (int mt = 0; mt < 4; ++mt)
#pragma unroll
        for (int nt = 0; nt < 2; ++nt)
          acc[mt][nt] = __builtin_amdgcn_mfma_f32_16x16x32_bf16(af[mt], bfr[nt], acc[mt][nt], 0, 0, 0);
    }

#pragma unroll
    for (int mt = 0; mt < 4; ++mt) {
#pragma unroll
      for (int nt = 0; nt < 2; ++nt) {
        const int col = c0 + nt * 16 + lr;
        const float bc2 = ob[col];
#pragma unroll
        for (int j = 0; j < 4; ++j) {
          const int tok = m0 + mt * 16 + g * 4 + j;
          out[tok * 256 + col] = acc[mt][nt][j] + bc2;
        }
      }
    }
  }
}

// ---------------------------------------------------------------------------
extern "C" void kernel_launch(void* const* d_in, const int* in_sizes, int n_in,
                              void* d_out, int out_size, void* d_ws, size_t ws_size,
                              hipStream_t stream)
{
  const float* x      = (const float*)d_in[0];
  const float* sinp   = (const float*)d_in[1];
  const float* cosp   = (const float*)d_in[2];
  const float* mask_h = (const float*)d_in[3];
  const float* mask_w = (const float*)d_in[4];
  const float* q_w    = (const float*)d_in[5];
  const float* q_b    = (const float*)d_in[6];
  const float* k_w    = (const float*)d_in[7];
  const float* k_b    = (const float*)d_in[8];
  const float* v_w    = (const float*)d_in[9];
  const float* v_b    = (const float*)d_in[10];
  const float* lepe_w = (const float*)d_in[11];
  const float* lepe_b = (const float*)d_in[12];
  const float* out_w  = (const float*)d_in[13];
  const float* out_b  = (const float*)d_in[14];

  unsigned char* ws = (unsigned char*)d_ws;
  const size_t SZ = 33554432;  // 65536*256*2 bytes
  u16* qr    = (u16*)(ws);
  u16* kr    = (u16*)(ws + SZ);
  u16* vv    = (u16*)(ws + 2 * SZ);
  u16* v1    = (u16*)(ws + 3 * SZ);
  u16* lepe  = (u16*)(ws + 4 * SZ);
  u16* wqkvT = (u16*)(ws + 5 * SZ);
  u16* owT   = (u16*)(ws + 5 * SZ + 393216);
  float* bias = (float*)(ws + 5 * SZ + 393216 + 131072);
  u16* attn_out = vv;  // v is dead after conv + attnW

  pack_kernel<<<1024, 256, 0, stream>>>(q_w, q_b, k_w, k_b, v_w, v_b, out_w, wqkvT, bias, owT);
  qkv_gemm_kernel<<<512, 256, 0, stream>>>(x, wqkvT, bias, sinp, cosp, qr, kr, vv);
  lepe_kernel<<<2048, 256, 0, stream>>>(vv, lepe_w, lepe_b, lepe);
  attn_kernel<<<1024, 256, 0, stream>>>(qr, kr, vv, mask_w, v1, 0);
  attn_kernel<<<1024, 256, 0, stream>>>(qr, kr, v1, mask_h, attn_out, 1);
  out_gemm_kernel<<<1024, 256, 0, stream>>>(attn_out, lepe, owT, out_b, (float*)d_out);
}